// Round 8
// baseline (460.705 us; speedup 1.0000x reference)
//
#include <hip/hip_runtime.h>
#include <math.h>

namespace {
constexpr int kT = 8, kL = 8, kN = 500, kD = 64, kK = 12;
constexpr int kLN  = kL * kN;        // 4000
constexpr int kTLN = kT * kL * kN;   // 32000
constexpr int kBUF = kTLN * kD;      // 2,048,000 floats
constexpr int XS = 68;               // padded LDS stride for X tiles
}

__device__ __forceinline__ float sigf(float v) { return 1.f / (1.f + __expf(-v)); }

// fp32x4 -> bf16x4 (RNE), packed into uint2.
__device__ __forceinline__ uint2 pack_bf16x4(float4 v) {
    auto r = [](float f) {
        unsigned u = __float_as_uint(f);
        u += 0x7FFFu + ((u >> 16) & 1u);
        return u >> 16;
    };
    uint2 o;
    o.x = r(v.x) | (r(v.y) << 16);
    o.y = r(v.z) | (r(v.w) << 16);
    return o;
}

// Stage a 32x64 f32 tile (global row stride 64) into LDS (stride XS).
__device__ __forceinline__ void stage_x32(const float* __restrict__ src, float* lds,
                                          int row0) {
    int r  = threadIdx.x >> 4;          // 0..15
    int c4 = (threadIdx.x & 15) << 2;
#pragma unroll
    for (int i = 0; i < 2; ++i) {
        int rr = r + 16 * i;
        float4 v = *reinterpret_cast<const float4*>(src + (size_t)(row0 + rr) * 64 + c4);
        *reinterpret_cast<float4*>(lds + rr * XS + c4) = v;
    }
}

// Stage K x 64 weight (row-major) into LDS, stride 64.
template <int K>
__device__ __forceinline__ void stage_w(const float* __restrict__ w, float* lds) {
    const float4* s = reinterpret_cast<const float4*>(w);
    float4* d = reinterpret_cast<float4*>(lds);
#pragma unroll
    for (int i = 0; i < K / 16; ++i)
        d[threadIdx.x + 256 * i] = s[threadIdx.x + 256 * i];
}

// 32-row tile core: thread owns rows {2*rblk, 2*rblk+1} x cols 4*cblk..+3. K=64.
// W (stride 64) may live in LDS or global (L1-resident) — inlined either way.
__device__ __forceinline__ void gemm_core32(const float* ldsx, const float* w,
                                            int rblk, int cblk, float4 acc[2]) {
#pragma unroll 4
    for (int k = 0; k < 64; k += 4) {
        float4 xv[2], wv[4];
#pragma unroll
        for (int i = 0; i < 2; ++i)
            xv[i] = *reinterpret_cast<const float4*>(ldsx + (2 * rblk + i) * XS + k);
#pragma unroll
        for (int d = 0; d < 4; ++d)
            wv[d] = *reinterpret_cast<const float4*>(w + (k + d) * 64 + 4 * cblk);
#pragma unroll
        for (int i = 0; i < 2; ++i) {
            float xs[4] = {xv[i].x, xv[i].y, xv[i].z, xv[i].w};
#pragma unroll
            for (int d = 0; d < 4; ++d) {
                acc[i].x = fmaf(xs[d], wv[d].x, acc[i].x);
                acc[i].y = fmaf(xs[d], wv[d].y, acc[i].y);
                acc[i].z = fmaf(xs[d], wv[d].z, acc[i].z);
                acc[i].w = fmaf(xs[d], wv[d].w, acc[i].w);
            }
        }
    }
}

// Dual-weight version sharing the X reads.
__device__ __forceinline__ void gemm_core32x2(const float* ldsx, const float* wa,
                                              const float* wb, int rblk, int cblk,
                                              float4 acca[2], float4 accb[2]) {
#pragma unroll 4
    for (int k = 0; k < 64; k += 4) {
        float4 xv[2], va[4], vb[4];
#pragma unroll
        for (int i = 0; i < 2; ++i)
            xv[i] = *reinterpret_cast<const float4*>(ldsx + (2 * rblk + i) * XS + k);
#pragma unroll
        for (int d = 0; d < 4; ++d) {
            va[d] = *reinterpret_cast<const float4*>(wa + (k + d) * 64 + 4 * cblk);
            vb[d] = *reinterpret_cast<const float4*>(wb + (k + d) * 64 + 4 * cblk);
        }
#pragma unroll
        for (int i = 0; i < 2; ++i) {
            float xs[4] = {xv[i].x, xv[i].y, xv[i].z, xv[i].w};
#pragma unroll
            for (int d = 0; d < 4; ++d) {
                acca[i].x = fmaf(xs[d], va[d].x, acca[i].x);
                acca[i].y = fmaf(xs[d], va[d].y, acca[i].y);
                acca[i].z = fmaf(xs[d], va[d].z, acca[i].z);
                acca[i].w = fmaf(xs[d], va[d].w, acca[i].w);
                accb[i].x = fmaf(xs[d], vb[d].x, accb[i].x);
                accb[i].y = fmaf(xs[d], vb[d].y, accb[i].y);
                accb[i].z = fmaf(xs[d], vb[d].z, accb[i].z);
                accb[i].w = fmaf(xs[d], vb[d].w, accb[i].w);
            }
        }
    }
}

// Score+softmax+combine for a 32-row tile -> O into ldsx. Q fp32 row-major,
// K bf16-packed (row = 16 uint2). Quarter-wave: 16 lanes/row, float4/lane.
__device__ __forceinline__ void score_phase32(const float* __restrict__ Qsrc,
                                              const uint2* __restrict__ Kb,
                                              const int* __restrict__ neigh,
                                              float* ldsx, int row0) {
    int lane = threadIdx.x & 63;
    int wv   = threadIdx.x >> 6;
    int sub  = lane >> 4;
    int gq   = lane & 15;
#pragma unroll 1
    for (int pp = 0; pp < 2; ++pp) {
        int lr  = pp * 16 + wv * 4 + sub;   // 0..31
        int row = row0 + lr;
        int n   = row % kN;
        int slab = row - n;
        float4 q = *(reinterpret_cast<const float4*>(Qsrc) + (size_t)row * 16 + gq);
        const int4* nbp = reinterpret_cast<const int4*>(neigh + n * kK);
        int4 nb0 = nbp[0], nb1 = nbp[1], nb2 = nbp[2];
        int nb[12] = {nb0.x, nb0.y, nb0.z, nb0.w, nb1.x, nb1.y, nb1.z, nb1.w,
                      nb2.x, nb2.y, nb2.z, nb2.w};
        float4 kv[12];
        float sc[12];
#pragma unroll
        for (int j = 0; j < 12; ++j) {
            uint2 kk = Kb[(size_t)(slab + nb[j]) * 16 + gq];
            kv[j].x = __uint_as_float(kk.x << 16);
            kv[j].y = __uint_as_float(kk.x & 0xFFFF0000u);
            kv[j].z = __uint_as_float(kk.y << 16);
            kv[j].w = __uint_as_float(kk.y & 0xFFFF0000u);
            sc[j] = q.x * kv[j].x + q.y * kv[j].y + q.z * kv[j].z + q.w * kv[j].w;
        }
#pragma unroll
        for (int off = 1; off < 16; off <<= 1) {
#pragma unroll
            for (int j = 0; j < 12; ++j) sc[j] += __shfl_xor(sc[j], off, 16);
        }
        float mx = sc[0];
#pragma unroll
        for (int j = 1; j < 12; ++j) mx = fmaxf(mx, sc[j]);
        float ssum = 0.f;
#pragma unroll
        for (int j = 0; j < 12; ++j) { sc[j] = __expf(sc[j] - mx); ssum += sc[j]; }
        float inv = 1.f / ssum;
        float4 o = q;
#pragma unroll
        for (int j = 0; j < 12; ++j) {
            float a = sc[j] * inv;
            o.x = fmaf(a, kv[j].x, o.x);
            o.y = fmaf(a, kv[j].y, o.y);
            o.z = fmaf(a, kv[j].z, o.z);
            o.w = fmaf(a, kv[j].w, o.w);
        }
        *reinterpret_cast<float4*>(ldsx + lr * XS + 4 * gq) = o;
    }
}

// Full evolution scan (row-local recurrence), 32-row tiles (125 blocks).
// Emits t=0 slab and now_final too.
__global__ void __launch_bounds__(256) evo_all_kernel(const float* __restrict__ stat,
                                                      const float* __restrict__ thre,
                                                      const float* __restrict__ dyn0,
                                                      float* __restrict__ all_dyn,
                                                      float* __restrict__ diff,
                                                      float* __restrict__ now_final,
                                                      const float* __restrict__ w1) {
    __shared__ float ldsn[32 * XS];
    __shared__ float ldss[32 * XS];
    __shared__ float ldsw[128 * 64];
    int row0 = blockIdx.x * 32;
    stage_x32(dyn0, ldsn, row0);
    stage_w<128>(w1, ldsw);
    int rblk = threadIdx.x >> 4, cblk = threadIdx.x & 15;
    __syncthreads();
#pragma unroll
    for (int i = 0; i < 2; ++i) {
        int row = row0 + 2 * rblk + i;
        float4 x0 = *reinterpret_cast<const float4*>(ldsn + (2 * rblk + i) * XS + 4 * cblk);
        *reinterpret_cast<float4*>(all_dyn + (size_t)row * 64 + 4 * cblk) = x0;
    }
#pragma unroll 1
    for (int t = 1; t < kT; ++t) {
        stage_x32(stat + (size_t)t * kLN * kD, ldss, row0);
        __syncthreads();
        float4 acc[2] = {};
        gemm_core32(ldsn, ldsw, rblk, cblk, acc);
        gemm_core32(ldss, ldsw + 64 * 64, rblk, cblk, acc);
        float4 nv[2];
#pragma unroll
        for (int i = 0; i < 2; ++i) {
            int row = row0 + 2 * rblk + i;
            float tt = thre[t * kLN + row];
            float4 xn = *reinterpret_cast<const float4*>(ldsn + (2 * rblk + i) * XS + 4 * cblk);
            nv[i].x = sigf(acc[i].x * tt + xn.x * (1.f - tt));
            nv[i].y = sigf(acc[i].y * tt + xn.y * (1.f - tt));
            nv[i].z = sigf(acc[i].z * tt + xn.z * (1.f - tt));
            nv[i].w = sigf(acc[i].w * tt + xn.w * (1.f - tt));
            float4 df;
            df.x = nv[i].x - xn.x; df.y = nv[i].y - xn.y;
            df.z = nv[i].z - xn.z; df.w = nv[i].w - xn.w;
            *reinterpret_cast<float4*>(all_dyn + ((size_t)t * kLN + row) * 64 + 4 * cblk) = nv[i];
            *reinterpret_cast<float4*>(diff + ((size_t)(t - 1) * kLN + row) * 64 + 4 * cblk) = df;
            if (t == kT - 1)
                *reinterpret_cast<float4*>(now_final + (size_t)row * 64 + 4 * cblk) = nv[i];
        }
        __syncthreads();
#pragma unroll
        for (int i = 0; i < 2; ++i)
            *reinterpret_cast<float4*>(ldsn + (2 * rblk + i) * XS + 4 * cblk) = nv[i];
    }
}

// Projections for step `step`, 6 chains (blockIdx.y=c), 32-row tiles.
// Q fp32 in-place over b1[c]; K bf16 -> b2[c]. Weights straight from global (L1).
__global__ void __launch_bounds__(256) gemm_qk(const float* __restrict__ Xdyn,
                                               const float* __restrict__ Xstat,
                                               const float* __restrict__ wq_all,
                                               const float* __restrict__ wk_all,
                                               float* __restrict__ b1,
                                               unsigned short* __restrict__ b2,
                                               int step) {
    __shared__ float ldsx[32 * XS];
    int c = blockIdx.y;
    int m = c / 3;
    float* b1c = b1 + (size_t)c * kBUF;
    unsigned short* kc = b2 + (size_t)c * kBUF;
    const float* X = step ? b1c : (m == 0 ? Xdyn : Xstat);
    const float* gwq = wq_all + (size_t)(c * 2 + step) * kD * kD;
    const float* gwk = wk_all + (size_t)(c * 2 + step) * kD * kD;
    int row0 = blockIdx.x * 32;
    stage_x32(X, ldsx, row0);
    __syncthreads();
    int rblk = threadIdx.x >> 4, cblk = threadIdx.x & 15;
    float4 aq[2] = {}, ak[2] = {};
    gemm_core32x2(ldsx, gwq, gwk, rblk, cblk, aq, ak);
#pragma unroll
    for (int i = 0; i < 2; ++i) {
        size_t row = row0 + 2 * rblk + i;
        *reinterpret_cast<float4*>(b1c + row * 64 + 4 * cblk) = aq[i];
        *reinterpret_cast<uint2*>(kc + row * 64 + 4 * cblk) = pack_bf16x4(ak[i]);
    }
}

// Fused score+softmax+combine+wd for step `step`, 32-row tiles, XCD-swizzled
// (grid 1000x6 = 6000 = 8 x 750: each XCD owns contiguous tiles of one chain).
// y = sigmoid(O@wd) written in-place over b1[c].
__global__ void __launch_bounds__(256) scorewd_kernel(float* __restrict__ b1,
                                                      const unsigned short* __restrict__ b2,
                                                      const int* __restrict__ npoi,
                                                      const int* __restrict__ nroad,
                                                      const int* __restrict__ nrec,
                                                      const float* __restrict__ wd_all,
                                                      int step) {
    __shared__ float ldsx[32 * XS];
    int p   = blockIdx.y * gridDim.x + blockIdx.x;
    int xcd = p & 7;
    int gid = xcd * 750 + (p >> 3);     // 0..5999
    int c    = gid / 1000;
    int tile = gid - c * 1000;
    int g = c % 3;
    float* b1c = b1 + (size_t)c * kBUF;
    const uint2* Kb = reinterpret_cast<const uint2*>(b2 + (size_t)c * kBUF);
    const int* neigh = (g == 0) ? npoi : (g == 1) ? nroad : nrec;
    const float* gwd = wd_all + (size_t)(c * 2 + step) * kD * kD;
    int row0 = tile * 32;

    score_phase32(b1c, Kb, neigh, ldsx, row0);
    __syncthreads();

    int rblk = threadIdx.x >> 4, cblk = threadIdx.x & 15;
    float4 acc[2] = {};
    gemm_core32(ldsx, gwd, rblk, cblk, acc);
#pragma unroll
    for (int i = 0; i < 2; ++i) {
        size_t idx = ((size_t)(row0 + 2 * rblk + i)) * 64 + 4 * cblk;
        float4 y;
        y.x = sigf(acc[i].x); y.y = sigf(acc[i].y);
        y.z = sigf(acc[i].z); y.w = sigf(acc[i].w);
        *reinterpret_cast<float4*>(b1c + idx) = y;
    }
}

// LSTM with mix fused: reads the 6 y buffers + wmix per l-step.
__global__ void __launch_bounds__(256) lstm_kernel(const float* __restrict__ b1,
                                                   const float* __restrict__ wmix,
                                                   const float* __restrict__ cw,
                                                   const float* __restrict__ cb,
                                                   float* __restrict__ hlast) {
    int lane = threadIdx.x & 63;
    int wv   = threadIdx.x >> 6;
    int sub  = lane >> 4;
    int fq   = lane & 15;
    int cell = blockIdx.x * 16 + wv * 4 + sub;   // 0..3999
    int t = cell / kN, n = cell % kN;
    float wd_[4][4], ws_[4][4], wh[4], bb[4];
#pragma unroll
    for (int gg = 0; gg < 4; ++gg) {
#pragma unroll
        for (int k = 0; k < 4; ++k) {
            wd_[gg][k] = cw[gg * 129 + fq * 4 + k];
            ws_[gg][k] = cw[gg * 129 + 64 + fq * 4 + k];
        }
        wh[gg] = cw[gg * 129 + 128];
        bb[gg] = cb[gg];
    }
    float4 wm[6];
#pragma unroll
    for (int j = 0; j < 6; ++j)
        wm[j] = *reinterpret_cast<const float4*>(wmix + j * 64 + fq * 4);
    float h = 0.f, cc = 0.f;
#pragma unroll 1
    for (int l = 0; l < kL; ++l) {
        size_t row16 = ((size_t)(t * kL + l) * kN + n) * 16 + fq;
        float4 y[6];
#pragma unroll
        for (int j = 0; j < 6; ++j)
            y[j] = *(reinterpret_cast<const float4*>(b1) + (size_t)j * (kBUF / 4) + row16);
        float4 xd, xs;
        xd.x = sigf(y[0].x * wm[0].x + y[1].x * wm[1].x + y[2].x * wm[2].x);
        xd.y = sigf(y[0].y * wm[0].y + y[1].y * wm[1].y + y[2].y * wm[2].y);
        xd.z = sigf(y[0].z * wm[0].z + y[1].z * wm[1].z + y[2].z * wm[2].z);
        xd.w = sigf(y[0].w * wm[0].w + y[1].w * wm[1].w + y[2].w * wm[2].w);
        xs.x = sigf(y[3].x * wm[3].x + y[4].x * wm[4].x + y[5].x * wm[5].x);
        xs.y = sigf(y[3].y * wm[3].y + y[4].y * wm[4].y + y[5].y * wm[5].y);
        xs.z = sigf(y[3].z * wm[3].z + y[4].z * wm[4].z + y[5].z * wm[5].z);
        xs.w = sigf(y[3].w * wm[3].w + y[4].w * wm[4].w + y[5].w * wm[5].w);
        float gsum[4];
#pragma unroll
        for (int gg = 0; gg < 4; ++gg) {
            float v = xd.x * wd_[gg][0] + xd.y * wd_[gg][1]
                    + xd.z * wd_[gg][2] + xd.w * wd_[gg][3];
            v += xs.x * ws_[gg][0] + xs.y * ws_[gg][1]
               + xs.z * ws_[gg][2] + xs.w * ws_[gg][3];
            gsum[gg] = v;
        }
#pragma unroll
        for (int off = 1; off < 16; off <<= 1) {
#pragma unroll
            for (int gg = 0; gg < 4; ++gg) gsum[gg] += __shfl_xor(gsum[gg], off, 16);
        }
        float gi = sigf(gsum[0] + bb[0] + h * wh[0]);
        float gf = sigf(gsum[1] + bb[1] + h * wh[1]);
        float go = sigf(gsum[2] + bb[2] + h * wh[2]);
        float gg_ = tanhf(gsum[3] + bb[3] + h * wh[3]);
        cc = gf * cc + gi * gg_;
        h = go * tanhf(cc);
    }
    if (fq == 0) hlast[cell] = h;
}

// out[t,m] = sigmoid(sum_n h[t,n]*fw[m,n] + fb[m]); one wave per output.
__global__ void final_kernel(const float* __restrict__ h, const float* __restrict__ fw,
                             const float* __restrict__ fb, float* __restrict__ out) {
    int wave = threadIdx.x >> 6, lane = threadIdx.x & 63;
    int o = blockIdx.x * 4 + wave;
    int t = o / kN, m = o % kN;
    float acc = 0.f;
    for (int n = lane; n < kN; n += 64)
        acc = fmaf(h[t * kN + n], fw[(size_t)m * kN + n], acc);
#pragma unroll
    for (int off = 32; off > 0; off >>= 1) acc += __shfl_xor(acc, off);
    if (lane == 0) out[o] = sigf(acc + fb[m]);
}

extern "C" void kernel_launch(void* const* d_in, const int* in_sizes, int n_in,
                              void* d_out, int out_size, void* d_ws, size_t ws_size,
                              hipStream_t stream) {
    const float* stat   = (const float*)d_in[0];
    const float* thre   = (const float*)d_in[1];
    const float* dyn0   = (const float*)d_in[2];
    const int*   npoi   = (const int*)d_in[3];
    const int*   nroad  = (const int*)d_in[4];
    const int*   nrec   = (const int*)d_in[5];
    const float* w1     = (const float*)d_in[6];
    const float* wq_all = (const float*)d_in[7];
    const float* wk_all = (const float*)d_in[8];
    const float* wd_all = (const float*)d_in[9];
    const float* wmix   = (const float*)d_in[10];
    const float* conv_w = (const float*)d_in[11];
    const float* conv_b = (const float*)d_in[12];
    const float* fin_w  = (const float*)d_in[13];
    const float* fin_b  = (const float*)d_in[14];

    float* out       = (float*)d_out;                 // (T,N)
    float* now_final = out + kT * kN;                 // (L,N,D)
    float* diffs     = now_final + (size_t)kLN * kD;  // (T-1,L,N,D)

    float* ws      = (float*)d_ws;
    float* all_dyn = ws;                              // 1 x kBUF
    float* b1      = ws + (size_t)kBUF;               // 6 x kBUF fp32 (Q/y)
    unsigned short* b2 = (unsigned short*)(ws + 7 * (size_t)kBUF);  // 6 x kBUF bf16 (K)
    float* hlast   = ws + 10 * (size_t)kBUF;          // (T,N)

    // ---- evolution scan ----
    evo_all_kernel<<<kLN / 32, 256, 0, stream>>>(stat, thre, dyn0,
                                                 all_dyn, diffs, now_final, w1);

    // ---- attention: 6 chains batched, 2 steps, 32-row tiles ----
    dim3 agrid(kTLN / 32, 6);
    gemm_qk<<<agrid, 256, 0, stream>>>(all_dyn, stat, wq_all, wk_all, b1, b2, 0);
    scorewd_kernel<<<agrid, 256, 0, stream>>>(b1, b2, npoi, nroad, nrec, wd_all, 0);
    gemm_qk<<<agrid, 256, 0, stream>>>(all_dyn, stat, wq_all, wk_all, b1, b2, 1);
    scorewd_kernel<<<agrid, 256, 0, stream>>>(b1, b2, npoi, nroad, nrec, wd_all, 1);

    // ---- LSTM (mix fused) over l, then final projection ----
    lstm_kernel<<<kT * kN / 16, 256, 0, stream>>>(b1, wmix, conv_w, conv_b, hlast);
    final_kernel<<<kT * kN / 4, 256, 0, stream>>>(hlast, fin_w, fin_b, out);
}

// Round 9
// 365.110 us; speedup vs baseline: 1.2618x; 1.2618x over previous
//
#include <hip/hip_runtime.h>
#include <math.h>

namespace {
constexpr int kT = 8, kL = 8, kN = 500, kD = 64, kK = 12;
constexpr int kLN  = kL * kN;        // 4000
constexpr int kTLN = kT * kL * kN;   // 32000
constexpr int kBUF = kTLN * kD;      // 2,048,000 elements
constexpr int XS = 68;               // padded LDS stride for X tiles
}

__device__ __forceinline__ float sigf(float v) { return 1.f / (1.f + __expf(-v)); }

// fp32x4 -> bf16x4 (RNE), packed into uint2.
__device__ __forceinline__ uint2 pack_bf16x4(float4 v) {
    auto r = [](float f) {
        unsigned u = __float_as_uint(f);
        u += 0x7FFFu + ((u >> 16) & 1u);
        return u >> 16;
    };
    uint2 o;
    o.x = r(v.x) | (r(v.y) << 16);
    o.y = r(v.z) | (r(v.w) << 16);
    return o;
}

__device__ __forceinline__ float4 unpack_bf16x4(uint2 kk) {
    float4 f;
    f.x = __uint_as_float(kk.x << 16);
    f.y = __uint_as_float(kk.x & 0xFFFF0000u);
    f.z = __uint_as_float(kk.y << 16);
    f.w = __uint_as_float(kk.y & 0xFFFF0000u);
    return f;
}

// Stage a 64x64 f32 tile (row stride 64) into LDS (stride XS); rows clamped to M.
__device__ __forceinline__ void stage_x(const float* __restrict__ src, float* lds,
                                        int row0, int M) {
    int r  = threadIdx.x >> 4;
    int c4 = (threadIdx.x & 15) << 2;
#pragma unroll
    for (int i = 0; i < 4; ++i) {
        int rr  = r + 16 * i;
        int row = row0 + rr;
        row = row < M ? row : M - 1;
        float4 v = *reinterpret_cast<const float4*>(src + (size_t)row * 64 + c4);
        *reinterpret_cast<float4*>(lds + rr * XS + c4) = v;
    }
}

// Stage a 64x64 bf16 tile into LDS as fp32.
__device__ __forceinline__ void stage_x_bf16(const unsigned short* __restrict__ src,
                                             float* lds, int row0) {
    int r  = threadIdx.x >> 4;
    int c4 = (threadIdx.x & 15) << 2;
#pragma unroll
    for (int i = 0; i < 4; ++i) {
        int rr = r + 16 * i;
        uint2 v = *reinterpret_cast<const uint2*>(src + (size_t)(row0 + rr) * 64 + c4);
        *reinterpret_cast<float4*>(lds + rr * XS + c4) = unpack_bf16x4(v);
    }
}

// Stage K x 64 weight (row-major) into LDS, stride 64.
template <int K>
__device__ __forceinline__ void stage_w(const float* __restrict__ w, float* lds) {
    const float4* s = reinterpret_cast<const float4*>(w);
    float4* d = reinterpret_cast<float4*>(lds);
#pragma unroll
    for (int i = 0; i < K / 16; ++i)
        d[threadIdx.x + 256 * i] = s[threadIdx.x + 256 * i];
}

// acc[i] += row(4*rblk+i) of Xtile @ W[:, 4*cblk..+3], K=64. W in LDS or global(L1).
__device__ __forceinline__ void gemm_core(const float* ldsx, const float* w,
                                          int rblk, int cblk, float4 acc[4]) {
#pragma unroll 4
    for (int k = 0; k < 64; k += 4) {
        float4 xv[4], wv[4];
#pragma unroll
        for (int i = 0; i < 4; ++i)
            xv[i] = *reinterpret_cast<const float4*>(ldsx + (4 * rblk + i) * XS + k);
#pragma unroll
        for (int d = 0; d < 4; ++d)
            wv[d] = *reinterpret_cast<const float4*>(w + (k + d) * 64 + 4 * cblk);
#pragma unroll
        for (int i = 0; i < 4; ++i) {
            float xs[4] = {xv[i].x, xv[i].y, xv[i].z, xv[i].w};
#pragma unroll
            for (int d = 0; d < 4; ++d) {
                acc[i].x = fmaf(xs[d], wv[d].x, acc[i].x);
                acc[i].y = fmaf(xs[d], wv[d].y, acc[i].y);
                acc[i].z = fmaf(xs[d], wv[d].z, acc[i].z);
                acc[i].w = fmaf(xs[d], wv[d].w, acc[i].w);
            }
        }
    }
}

// Dual-weight version sharing the X reads (both weights global/L1).
__device__ __forceinline__ void gemm_core2(const float* ldsx, const float* wa,
                                           const float* wb, int rblk, int cblk,
                                           float4 acca[4], float4 accb[4]) {
#pragma unroll 4
    for (int k = 0; k < 64; k += 4) {
        float4 xv[4], va[4], vb[4];
#pragma unroll
        for (int i = 0; i < 4; ++i)
            xv[i] = *reinterpret_cast<const float4*>(ldsx + (4 * rblk + i) * XS + k);
#pragma unroll
        for (int d = 0; d < 4; ++d) {
            va[d] = *reinterpret_cast<const float4*>(wa + (k + d) * 64 + 4 * cblk);
            vb[d] = *reinterpret_cast<const float4*>(wb + (k + d) * 64 + 4 * cblk);
        }
#pragma unroll
        for (int i = 0; i < 4; ++i) {
            float xs[4] = {xv[i].x, xv[i].y, xv[i].z, xv[i].w};
#pragma unroll
            for (int d = 0; d < 4; ++d) {
                acca[i].x = fmaf(xs[d], va[d].x, acca[i].x);
                acca[i].y = fmaf(xs[d], va[d].y, acca[i].y);
                acca[i].z = fmaf(xs[d], va[d].z, acca[i].z);
                acca[i].w = fmaf(xs[d], va[d].w, acca[i].w);
                accb[i].x = fmaf(xs[d], vb[d].x, accb[i].x);
                accb[i].y = fmaf(xs[d], vb[d].y, accb[i].y);
                accb[i].z = fmaf(xs[d], vb[d].z, accb[i].z);
                accb[i].w = fmaf(xs[d], vb[d].w, accb[i].w);
            }
        }
    }
}

// Score+softmax+combine for a 64-row tile -> O (fp32) into ldsx.
// Q bf16 (row = 16 uint2), K bf16. Quarter-wave: 16 lanes/row, 4 vals/lane.
__device__ __forceinline__ void score_phase(const uint2* __restrict__ Qb,
                                            const uint2* __restrict__ Kb,
                                            const int* __restrict__ neigh,
                                            float* ldsx, int row0) {
    int lane = threadIdx.x & 63;
    int wv   = threadIdx.x >> 6;
    int sub  = lane >> 4;
    int gq   = lane & 15;
#pragma unroll 1
    for (int pp = 0; pp < 4; ++pp) {
        int lr  = pp * 16 + wv * 4 + sub;    // local row 0..63
        int row = row0 + lr;
        int n   = row % kN;
        int slab = row - n;
        float4 q = unpack_bf16x4(Qb[(size_t)row * 16 + gq]);
        const int4* nbp = reinterpret_cast<const int4*>(neigh + n * kK);
        int4 nb0 = nbp[0], nb1 = nbp[1], nb2 = nbp[2];
        int nb[12] = {nb0.x, nb0.y, nb0.z, nb0.w, nb1.x, nb1.y, nb1.z, nb1.w,
                      nb2.x, nb2.y, nb2.z, nb2.w};
        float4 kv[12];
        float sc[12];
#pragma unroll
        for (int j = 0; j < 12; ++j) {
            kv[j] = unpack_bf16x4(Kb[(size_t)(slab + nb[j]) * 16 + gq]);
            sc[j] = q.x * kv[j].x + q.y * kv[j].y + q.z * kv[j].z + q.w * kv[j].w;
        }
#pragma unroll
        for (int off = 1; off < 16; off <<= 1) {
#pragma unroll
            for (int j = 0; j < 12; ++j) sc[j] += __shfl_xor(sc[j], off, 16);
        }
        float mx = sc[0];
#pragma unroll
        for (int j = 1; j < 12; ++j) mx = fmaxf(mx, sc[j]);
        float ssum = 0.f;
#pragma unroll
        for (int j = 0; j < 12; ++j) { sc[j] = __expf(sc[j] - mx); ssum += sc[j]; }
        float inv = 1.f / ssum;
        float4 o = q;
#pragma unroll
        for (int j = 0; j < 12; ++j) {
            float a = sc[j] * inv;
            o.x = fmaf(a, kv[j].x, o.x);
            o.y = fmaf(a, kv[j].y, o.y);
            o.z = fmaf(a, kv[j].z, o.z);
            o.w = fmaf(a, kv[j].w, o.w);
        }
        *reinterpret_cast<float4*>(ldsx + lr * XS + 4 * gq) = o;
    }
}

// Full evolution scan (row-local recurrence, 64-row tiles); emits t=0 slab and now_final.
__global__ void __launch_bounds__(256) evo_all_kernel(const float* __restrict__ stat,
                                                      const float* __restrict__ thre,
                                                      const float* __restrict__ dyn0,
                                                      float* __restrict__ all_dyn,
                                                      float* __restrict__ diff,
                                                      float* __restrict__ now_final,
                                                      const float* __restrict__ w1) {
    __shared__ float ldsn[64 * XS];
    __shared__ float ldss[64 * XS];
    __shared__ float ldsw[128 * 64];
    int row0 = blockIdx.x * 64;
    stage_x(dyn0, ldsn, row0, kLN);
    stage_w<128>(w1, ldsw);
    int rblk = threadIdx.x >> 4, cblk = threadIdx.x & 15;
    __syncthreads();
#pragma unroll
    for (int i = 0; i < 4; ++i) {
        int row = row0 + 4 * rblk + i;
        if (row < kLN) {
            float4 x0 = *reinterpret_cast<const float4*>(ldsn + (4 * rblk + i) * XS + 4 * cblk);
            *reinterpret_cast<float4*>(all_dyn + (size_t)row * 64 + 4 * cblk) = x0;
        }
    }
#pragma unroll 1
    for (int t = 1; t < kT; ++t) {
        stage_x(stat + (size_t)t * kLN * kD, ldss, row0, kLN);
        __syncthreads();
        float4 acc[4] = {};
        gemm_core(ldsn, ldsw, rblk, cblk, acc);
        gemm_core(ldss, ldsw + 64 * 64, rblk, cblk, acc);
        float4 nv[4];
#pragma unroll
        for (int i = 0; i < 4; ++i) {
            int row = row0 + 4 * rblk + i;
            int rc  = row < kLN ? row : kLN - 1;
            float tt = thre[t * kLN + rc];
            float4 xn = *reinterpret_cast<const float4*>(ldsn + (4 * rblk + i) * XS + 4 * cblk);
            nv[i].x = sigf(acc[i].x * tt + xn.x * (1.f - tt));
            nv[i].y = sigf(acc[i].y * tt + xn.y * (1.f - tt));
            nv[i].z = sigf(acc[i].z * tt + xn.z * (1.f - tt));
            nv[i].w = sigf(acc[i].w * tt + xn.w * (1.f - tt));
            if (row < kLN) {
                float4 df;
                df.x = nv[i].x - xn.x; df.y = nv[i].y - xn.y;
                df.z = nv[i].z - xn.z; df.w = nv[i].w - xn.w;
                *reinterpret_cast<float4*>(all_dyn + ((size_t)t * kLN + row) * 64 + 4 * cblk) = nv[i];
                *reinterpret_cast<float4*>(diff + ((size_t)(t - 1) * kLN + row) * 64 + 4 * cblk) = df;
                if (t == kT - 1)
                    *reinterpret_cast<float4*>(now_final + (size_t)row * 64 + 4 * cblk) = nv[i];
            }
        }
        __syncthreads();
#pragma unroll
        for (int i = 0; i < 4; ++i)
            *reinterpret_cast<float4*>(ldsn + (4 * rblk + i) * XS + 4 * cblk) = nv[i];
    }
}

// Projections for step `step`, 6 chains (blockIdx.y=c), 64-row tiles.
// Step0 X: all_dyn/stat (fp32); step1 X: b1[c] (bf16 y0). Q bf16 in-place over
// b1[c]; K bf16 -> b2[c]. Weights straight from global (L1-resident).
__global__ void __launch_bounds__(256) gemm_qk(const float* __restrict__ Xdyn,
                                               const float* __restrict__ Xstat,
                                               const float* __restrict__ wq_all,
                                               const float* __restrict__ wk_all,
                                               unsigned short* __restrict__ b1,
                                               unsigned short* __restrict__ b2,
                                               int step) {
    __shared__ float ldsx[64 * XS];
    int c = blockIdx.y;
    int m = c / 3;
    unsigned short* b1c = b1 + (size_t)c * kBUF;
    unsigned short* kc  = b2 + (size_t)c * kBUF;
    const float* gwq = wq_all + (size_t)(c * 2 + step) * kD * kD;
    const float* gwk = wk_all + (size_t)(c * 2 + step) * kD * kD;
    int row0 = blockIdx.x * 64;
    if (step) stage_x_bf16(b1c, ldsx, row0);
    else      stage_x(m == 0 ? Xdyn : Xstat, ldsx, row0, kTLN);
    __syncthreads();
    int rblk = threadIdx.x >> 4, cblk = threadIdx.x & 15;
    float4 aq[4] = {}, ak[4] = {};
    gemm_core2(ldsx, gwq, gwk, rblk, cblk, aq, ak);
#pragma unroll
    for (int i = 0; i < 4; ++i) {
        size_t row = row0 + 4 * rblk + i;
        *reinterpret_cast<uint2*>(b1c + row * 64 + 4 * cblk) = pack_bf16x4(aq[i]);
        *reinterpret_cast<uint2*>(kc + row * 64 + 4 * cblk)  = pack_bf16x4(ak[i]);
    }
}

// Fused score+softmax+combine+wd for step `step`, 64-row tiles, XCD-swizzled
// (3000 blocks = 8 x 375). y = sigmoid(O@wd) bf16 in-place over b1[c].
__global__ void __launch_bounds__(256) scorewd_kernel(unsigned short* __restrict__ b1,
                                                      const unsigned short* __restrict__ b2,
                                                      const int* __restrict__ npoi,
                                                      const int* __restrict__ nroad,
                                                      const int* __restrict__ nrec,
                                                      const float* __restrict__ wd_all,
                                                      int step) {
    __shared__ float ldsx[64 * XS];
    int p   = blockIdx.y * gridDim.x + blockIdx.x;
    int xcd = p & 7;
    int gid = xcd * 375 + (p >> 3);      // 0..2999
    int c    = gid / 500;
    int tile = gid - c * 500;
    int g = c % 3;
    unsigned short* b1c = b1 + (size_t)c * kBUF;
    const uint2* Qb = reinterpret_cast<const uint2*>(b1c);
    const uint2* Kb = reinterpret_cast<const uint2*>(b2 + (size_t)c * kBUF);
    const int* neigh = (g == 0) ? npoi : (g == 1) ? nroad : nrec;
    const float* gwd = wd_all + (size_t)(c * 2 + step) * kD * kD;
    int row0 = tile * 64;

    score_phase(Qb, Kb, neigh, ldsx, row0);
    __syncthreads();

    int rblk = threadIdx.x >> 4, cblk = threadIdx.x & 15;
    float4 acc[4] = {};
    gemm_core(ldsx, gwd, rblk, cblk, acc);
#pragma unroll
    for (int i = 0; i < 4; ++i) {
        size_t row = row0 + 4 * rblk + i;
        float4 y;
        y.x = sigf(acc[i].x); y.y = sigf(acc[i].y);
        y.z = sigf(acc[i].z); y.w = sigf(acc[i].w);
        *reinterpret_cast<uint2*>(b1c + row * 64 + 4 * cblk) = pack_bf16x4(y);
    }
}

// LSTM with mix fused: reads the 6 bf16 y buffers + wmix per l-step.
__global__ void __launch_bounds__(256) lstm_kernel(const unsigned short* __restrict__ b1,
                                                   const float* __restrict__ wmix,
                                                   const float* __restrict__ cw,
                                                   const float* __restrict__ cb,
                                                   float* __restrict__ hlast) {
    int lane = threadIdx.x & 63;
    int wv   = threadIdx.x >> 6;
    int sub  = lane >> 4;
    int fq   = lane & 15;
    int cell = blockIdx.x * 16 + wv * 4 + sub;   // 0..3999
    int t = cell / kN, n = cell % kN;
    float wd_[4][4], ws_[4][4], wh[4], bb[4];
#pragma unroll
    for (int gg = 0; gg < 4; ++gg) {
#pragma unroll
        for (int k = 0; k < 4; ++k) {
            wd_[gg][k] = cw[gg * 129 + fq * 4 + k];
            ws_[gg][k] = cw[gg * 129 + 64 + fq * 4 + k];
        }
        wh[gg] = cw[gg * 129 + 128];
        bb[gg] = cb[gg];
    }
    float4 wm[6];
#pragma unroll
    for (int j = 0; j < 6; ++j)
        wm[j] = *reinterpret_cast<const float4*>(wmix + j * 64 + fq * 4);
    float h = 0.f, cc = 0.f;
#pragma unroll 1
    for (int l = 0; l < kL; ++l) {
        size_t base = ((size_t)(t * kL + l) * kN + n) * 64 + fq * 4;
        float4 y[6];
#pragma unroll
        for (int j = 0; j < 6; ++j)
            y[j] = unpack_bf16x4(*reinterpret_cast<const uint2*>(b1 + (size_t)j * kBUF + base));
        float4 xd, xs;
        xd.x = sigf(y[0].x * wm[0].x + y[1].x * wm[1].x + y[2].x * wm[2].x);
        xd.y = sigf(y[0].y * wm[0].y + y[1].y * wm[1].y + y[2].y * wm[2].y);
        xd.z = sigf(y[0].z * wm[0].z + y[1].z * wm[1].z + y[2].z * wm[2].z);
        xd.w = sigf(y[0].w * wm[0].w + y[1].w * wm[1].w + y[2].w * wm[2].w);
        xs.x = sigf(y[3].x * wm[3].x + y[4].x * wm[4].x + y[5].x * wm[5].x);
        xs.y = sigf(y[3].y * wm[3].y + y[4].y * wm[4].y + y[5].y * wm[5].y);
        xs.z = sigf(y[3].z * wm[3].z + y[4].z * wm[4].z + y[5].z * wm[5].z);
        xs.w = sigf(y[3].w * wm[3].w + y[4].w * wm[4].w + y[5].w * wm[5].w);
        float gsum[4];
#pragma unroll
        for (int gg = 0; gg < 4; ++gg) {
            float v = xd.x * wd_[gg][0] + xd.y * wd_[gg][1]
                    + xd.z * wd_[gg][2] + xd.w * wd_[gg][3];
            v += xs.x * ws_[gg][0] + xs.y * ws_[gg][1]
               + xs.z * ws_[gg][2] + xs.w * ws_[gg][3];
            gsum[gg] = v;
        }
#pragma unroll
        for (int off = 1; off < 16; off <<= 1) {
#pragma unroll
            for (int gg = 0; gg < 4; ++gg) gsum[gg] += __shfl_xor(gsum[gg], off, 16);
        }
        float gi = sigf(gsum[0] + bb[0] + h * wh[0]);
        float gf = sigf(gsum[1] + bb[1] + h * wh[1]);
        float go = sigf(gsum[2] + bb[2] + h * wh[2]);
        float gg_ = tanhf(gsum[3] + bb[3] + h * wh[3]);
        cc = gf * cc + gi * gg_;
        h = go * tanhf(cc);
    }
    if (fq == 0) hlast[cell] = h;
}

// out[t,m] = sigmoid(sum_n h[t,n]*fw[m,n] + fb[m]); one wave per output.
__global__ void final_kernel(const float* __restrict__ h, const float* __restrict__ fw,
                             const float* __restrict__ fb, float* __restrict__ out) {
    int wave = threadIdx.x >> 6, lane = threadIdx.x & 63;
    int o = blockIdx.x * 4 + wave;
    int t = o / kN, m = o % kN;
    float acc = 0.f;
    for (int n = lane; n < kN; n += 64)
        acc = fmaf(h[t * kN + n], fw[(size_t)m * kN + n], acc);
#pragma unroll
    for (int off = 32; off > 0; off >>= 1) acc += __shfl_xor(acc, off);
    if (lane == 0) out[o] = sigf(acc + fb[m]);
}

extern "C" void kernel_launch(void* const* d_in, const int* in_sizes, int n_in,
                              void* d_out, int out_size, void* d_ws, size_t ws_size,
                              hipStream_t stream) {
    const float* stat   = (const float*)d_in[0];
    const float* thre   = (const float*)d_in[1];
    const float* dyn0   = (const float*)d_in[2];
    const int*   npoi   = (const int*)d_in[3];
    const int*   nroad  = (const int*)d_in[4];
    const int*   nrec   = (const int*)d_in[5];
    const float* w1     = (const float*)d_in[6];
    const float* wq_all = (const float*)d_in[7];
    const float* wk_all = (const float*)d_in[8];
    const float* wd_all = (const float*)d_in[9];
    const float* wmix   = (const float*)d_in[10];
    const float* conv_w = (const float*)d_in[11];
    const float* conv_b = (const float*)d_in[12];
    const float* fin_w  = (const float*)d_in[13];
    const float* fin_b  = (const float*)d_in[14];

    float* out       = (float*)d_out;                 // (T,N)
    float* now_final = out + kT * kN;                 // (L,N,D)
    float* diffs     = now_final + (size_t)kLN * kD;  // (T-1,L,N,D)

    float* ws      = (float*)d_ws;
    float* all_dyn = ws;                              // kBUF fp32
    unsigned short* b1 = (unsigned short*)(ws + (size_t)kBUF);      // 6 x kBUF bf16 (Q/y)
    unsigned short* b2 = (unsigned short*)(ws + 4 * (size_t)kBUF);  // 6 x kBUF bf16 (K)
    float* hlast   = ws + 7 * (size_t)kBUF;           // (T,N)

    // ---- evolution scan ----
    evo_all_kernel<<<(kLN + 63) / 64, 256, 0, stream>>>(stat, thre, dyn0,
                                                        all_dyn, diffs, now_final, w1);

    // ---- attention: 6 chains batched, 2 steps, 64-row tiles, bf16 intermediates ----
    dim3 agrid(kTLN / 64, 6);
    gemm_qk<<<agrid, 256, 0, stream>>>(all_dyn, stat, wq_all, wk_all, b1, b2, 0);
    scorewd_kernel<<<agrid, 256, 0, stream>>>(b1, b2, npoi, nroad, nrec, wd_all, 0);
    gemm_qk<<<agrid, 256, 0, stream>>>(all_dyn, stat, wq_all, wk_all, b1, b2, 1);
    scorewd_kernel<<<agrid, 256, 0, stream>>>(b1, b2, npoi, nroad, nrec, wd_all, 1);

    // ---- LSTM (mix fused) over l, then final projection ----
    lstm_kernel<<<kT * kN / 16, 256, 0, stream>>>(b1, wmix, conv_w, conv_b, hlast);
    final_kernel<<<kT * kN / 4, 256, 0, stream>>>(hlast, fin_w, fin_b, out);
}